// Round 4
// baseline (1094.461 us; speedup 1.0000x reference)
//
#include <hip/hip_runtime.h>
#include <math.h>

#define NTREE 512
#define NNODE 48
#define HD 256
#define LD 64
#define VOC 800
#define TSTEP 94
#define NFWD 47

typedef __attribute__((ext_vector_type(8))) short s8v;   // 8 bf16 (4 VGPRs)
typedef __attribute__((ext_vector_type(4))) float f4v;   // 4 fp32 acc

__device__ __forceinline__ float sigm(float x) { return 1.f / (1.f + expf(-x)); }

__device__ __forceinline__ float bfu(unsigned short u) {
    union { unsigned int i; float f; } c; c.i = ((unsigned int)u) << 16; return c.f;
}
__device__ __forceinline__ unsigned short f2bf(float f) {
    union { float f; unsigned int u; } c; c.f = f;
    return (unsigned short)((c.u + 0x7fffu + ((c.u >> 16) & 1u)) >> 16);
}
__device__ __forceinline__ s8v frag(const unsigned short* p) {
    union { int4 i; s8v v; } u; u.i = *(const int4*)p; return u.v;
}
__device__ __forceinline__ s8v zfrag() {
    union { int4 i; s8v v; } u; u.i = make_int4(0, 0, 0, 0); return u.v;
}

// ---------------------------------------------------------------------------
// Precompute x-projections for all 800 vocab words (biases folded in).
// ---------------------------------------------------------------------------
#define PV 8
__global__ __launch_bounds__(256) void prep_xproj(
    const float* __restrict__ emb,
    const float* __restrict__ Wz, const float* __restrict__ bz,
    const float* __restrict__ Wh, const float* __restrict__ bh,
    const float* __restrict__ Wr, const float* __restrict__ br,
    float* __restrict__ xzT, float* __restrict__ xhT, float* __restrict__ xrT)
{
    __shared__ float embL[PV][HD];
    const int j = threadIdx.x;
    const int v0 = blockIdx.x * PV;
    for (int r = 0; r < PV; ++r) embL[r][j] = emb[(v0 + r) * HD + j];
    __syncthreads();

    float az[PV], ah[PV], ar[PV];
#pragma unroll
    for (int r = 0; r < PV; ++r) { az[r] = bz[j]; ah[r] = bh[j]; ar[r] = br[j]; }
    for (int i = 0; i < HD; i += 4) {
        float wz0 = Wz[(i + 0) * HD + j], wz1 = Wz[(i + 1) * HD + j];
        float wz2 = Wz[(i + 2) * HD + j], wz3 = Wz[(i + 3) * HD + j];
        float wh0 = Wh[(i + 0) * HD + j], wh1 = Wh[(i + 1) * HD + j];
        float wh2 = Wh[(i + 2) * HD + j], wh3 = Wh[(i + 3) * HD + j];
        float wr0 = Wr[(i + 0) * HD + j], wr1 = Wr[(i + 1) * HD + j];
        float wr2 = Wr[(i + 2) * HD + j], wr3 = Wr[(i + 3) * HD + j];
#pragma unroll
        for (int r = 0; r < PV; ++r) {
            float4 e = *(const float4*)&embL[r][i];
            az[r] += e.x * wz0 + e.y * wz1 + e.z * wz2 + e.w * wz3;
            ah[r] += e.x * wh0 + e.y * wh1 + e.z * wh2 + e.w * wh3;
            ar[r] += e.x * wr0 + e.y * wr1 + e.z * wr2 + e.w * wr3;
        }
    }
#pragma unroll
    for (int r = 0; r < PV; ++r) {
        xzT[(v0 + r) * HD + j] = az[r];
        xhT[(v0 + r) * HD + j] = ah[r];
        xrT[(v0 + r) * HD + j] = ar[r];
    }
}

// Generic transpose-convert: dst[n][k] (bf16) = src[k][n] (f32). grid = N rows.
__global__ void tcvt(unsigned short* __restrict__ dst, const float* __restrict__ src,
                     int K, int N)
{
    int n = blockIdx.x;
    for (int k = threadIdx.x; k < K; k += 256)
        dst[n * K + k] = f2bf(src[k * N + n]);
}

__global__ void cvt_bf16(unsigned short* __restrict__ dst, const float* __restrict__ src, int n)
{
    int idx = blockIdx.x * 256 + threadIdx.x;
    if (idx < n) dst[idx] = f2bf(src[idx]);
}

// ---------------------------------------------------------------------------
// GRU, MFMA version. 256 wgs x 512 threads (8 waves), 2 trees/wg.
// Per step: [stage + MFMA phase A (az: waves 0-3 on WzT, ah: waves 4-7 on WhT)]
//   | finA (z, mt, m_e, h store) | MFMA phase B (ar, 2 tiles/wave on UrT)
//   | finB (r, arm). A rows 0-1 = trees, rows 2-15 zero. Weights streamed
//   from L2 as pre-transposed bf16 [n][k]. L2-BW-bound: ~393 KB/wg/step.
// ---------------------------------------------------------------------------
__global__ __launch_bounds__(512) void gru3(
    const int* __restrict__ wid,
    const float* __restrict__ xzT, const float* __restrict__ xhT,
    const float* __restrict__ xrT,
    const unsigned short* __restrict__ WzT, const unsigned short* __restrict__ WhT,
    const unsigned short* __restrict__ UrT,
    unsigned short* __restrict__ hsb)
{
    __shared__ float xzL[2][HD], xhL[2][HD], xrL[2][HD];
    __shared__ float azL[2][HD], ahL[2][HD], arL[2][HD];
    __shared__ float mF[2][HD];
    __shared__ unsigned short mB[2][HD], armB[2][HD];

    const int tid = threadIdx.x;
    const int wave = tid >> 6, lane = tid & 63;
    const int lq = lane >> 4, ln = lane & 15;
    const int trF = tid >> 8, chF = tid & 255;
    const int b0 = blockIdx.x * 2;

    for (int t = 0; t < TSTEP; ++t) {
        const bool fwd = t < NFWD;
        const int u = TSTEP - t;
        const int src = fwd ? t : u;
        const int dst = fwd ? (t + 1) : (u - 1);
        const bool hp = (t != 0) && (t != NFWD);

        // ---- stage: gathered x-projections + backtrack h prefetch ----
        {
            const int wsrc = wid[(b0 + trF) * NNODE + src];
            const int wdst = wid[(b0 + trF) * NNODE + dst];
            xzL[trF][chF] = xzT[wsrc * HD + chF];
            xhL[trF][chF] = xhT[wsrc * HD + chF];
            xrL[trF][chF] = xrT[wdst * HD + chF];
        }
        float hsp = 0.f;
        if (!fwd && dst > 0)
            hsp = bfu(hsb[((dst - 1) * NTREE + b0 + trF) * HD + chF]);

        // ---- MFMA phase A: az (waves 0-3, A=mB) / ah (waves 4-7, A=armB) ----
        if (hp) {
            const unsigned short* Ab = (wave < 4) ? &mB[0][0] : &armB[0][0];
            const unsigned short* WT = (wave < 4) ? WzT : WhT;
            const int tb = (wave & 3) * 4;           // 4 N-tiles per wave
            f4v c0 = (f4v){0.f,0.f,0.f,0.f}, c1 = c0, c2 = c0, c3 = c0;
#pragma unroll
            for (int kt = 0; kt < 8; ++kt) {
                s8v a = (ln < 2) ? frag(&Ab[ln * HD + kt * 32 + lq * 8]) : zfrag();
                const int ko = kt * 32 + lq * 8;
                s8v b0f = frag(&WT[((tb + 0) * 16 + ln) * HD + ko]);
                s8v b1f = frag(&WT[((tb + 1) * 16 + ln) * HD + ko]);
                s8v b2f = frag(&WT[((tb + 2) * 16 + ln) * HD + ko]);
                s8v b3f = frag(&WT[((tb + 3) * 16 + ln) * HD + ko]);
                c0 = __builtin_amdgcn_mfma_f32_16x16x32_bf16(a, b0f, c0, 0, 0, 0);
                c1 = __builtin_amdgcn_mfma_f32_16x16x32_bf16(a, b1f, c1, 0, 0, 0);
                c2 = __builtin_amdgcn_mfma_f32_16x16x32_bf16(a, b2f, c2, 0, 0, 0);
                c3 = __builtin_amdgcn_mfma_f32_16x16x32_bf16(a, b3f, c3, 0, 0, 0);
            }
            if (lq == 0) {
                float* OUT = (wave < 4) ? &azL[0][0] : &ahL[0][0];
                OUT[0 * HD + (tb + 0) * 16 + ln] = c0[0]; OUT[1 * HD + (tb + 0) * 16 + ln] = c0[1];
                OUT[0 * HD + (tb + 1) * 16 + ln] = c1[0]; OUT[1 * HD + (tb + 1) * 16 + ln] = c1[1];
                OUT[0 * HD + (tb + 2) * 16 + ln] = c2[0]; OUT[1 * HD + (tb + 2) * 16 + ln] = c2[1];
                OUT[0 * HD + (tb + 3) * 16 + ln] = c3[0]; OUT[1 * HD + (tb + 3) * 16 + ln] = c3[1];
            }
        }
        __syncthreads();

        // ---- finalize A: z, mt, m_e, h_v store ----
        {
            float az = xzL[trF][chF], ah = xhL[trF][chF], sold = 0.f;
            if (hp) {
                az += azL[trF][chF];
                ah += ahL[trF][chF];
                sold = mF[trF][chF];
            }
            float z = sigm(az), mt = tanhf(ah);
            float me = sold + z * (mt - sold);
            float hv = fwd ? me : (me + hsp);
            hsb[(t * NTREE + b0 + trF) * HD + chF] = f2bf(hv);
            mF[trF][chF] = me;
            mB[trF][chF] = f2bf(me);
        }
        __syncthreads();

        // ---- MFMA phase B: ar = m_e @ Ur (2 tiles/wave) ----
        {
            const int tb = wave * 2;
            f4v c0 = (f4v){0.f,0.f,0.f,0.f}, c1 = c0;
#pragma unroll
            for (int kt = 0; kt < 8; ++kt) {
                s8v a = (ln < 2) ? frag(&mB[ln][kt * 32 + lq * 8]) : zfrag();
                const int ko = kt * 32 + lq * 8;
                s8v b0f = frag(&UrT[((tb + 0) * 16 + ln) * HD + ko]);
                s8v b1f = frag(&UrT[((tb + 1) * 16 + ln) * HD + ko]);
                c0 = __builtin_amdgcn_mfma_f32_16x16x32_bf16(a, b0f, c0, 0, 0, 0);
                c1 = __builtin_amdgcn_mfma_f32_16x16x32_bf16(a, b1f, c1, 0, 0, 0);
            }
            if (lq == 0) {
                arL[0][(tb + 0) * 16 + ln] = c0[0]; arL[1][(tb + 0) * 16 + ln] = c0[1];
                arL[0][(tb + 1) * 16 + ln] = c1[0]; arL[1][(tb + 1) * 16 + ln] = c1[1];
            }
        }
        __syncthreads();

        // ---- finalize B: r, arm ----
        armB[trF][chF] = f2bf(sigm(arL[trF][chF] + xrL[trF][chF]) * mF[trF][chF]);
        __syncthreads();
    }
}

// ---------------------------------------------------------------------------
// Q head, MFMA. 768 wgs (48 trow x 16 tree-groups) x 256 thr. 32 rows/wg.
// ---------------------------------------------------------------------------
#define QG 32
__global__ __launch_bounds__(256) void q3(
    const int* __restrict__ wid,
    const unsigned short* __restrict__ tvB,
    const unsigned short* __restrict__ hsb,
    const unsigned short* __restrict__ W1T,
    const unsigned short* __restrict__ WoT,
    const float* __restrict__ Wb,
    const float* __restrict__ Wob,
    float* __restrict__ acc)
{
    __shared__ unsigned short X1L[QG][328];
    __shared__ unsigned short hidL[QG][264];
    __shared__ int tgts[QG];
    __shared__ float wred[4][QG][4];
    const int tid = threadIdx.x;
    const int wave = tid >> 6, lane = tid & 63;
    const int lq = lane >> 4, ln = lane & 15;
    const int trow = blockIdx.x >> 4;
    const int b0 = (blockIdx.x & 15) * QG;

    if (tid < QG) tgts[tid] = wid[(b0 + tid) * NNODE + trow];
    if (trow == 0) {
        int4 z = make_int4(0, 0, 0, 0);
        for (int idx = tid; idx < QG * 32; idx += 256) {
            int m = idx >> 5, c = idx & 31;
            *(int4*)&X1L[m][c * 8] = z;
        }
    } else {
        const unsigned short* hrow = hsb + (size_t)(trow - 1) * NTREE * HD;
        for (int idx = tid; idx < QG * 32; idx += 256) {
            int m = idx >> 5, c = idx & 31;
            *(int4*)&X1L[m][c * 8] = *(const int4*)&hrow[(b0 + m) * HD + c * 8];
        }
    }
    for (int idx = tid; idx < QG * 8; idx += 256) {
        int m = idx >> 3, c = idx & 7;
        *(int4*)&X1L[m][256 + c * 8] = *(const int4*)&tvB[(b0 + m) * LD + c * 8];
    }
    __syncthreads();

    f4v acc1[2][4];
#pragma unroll
    for (int mt = 0; mt < 2; ++mt)
#pragma unroll
        for (int nt = 0; nt < 4; ++nt) acc1[mt][nt] = (f4v){0.f, 0.f, 0.f, 0.f};
#pragma unroll
    for (int kt = 0; kt < 10; ++kt) {
        s8v a0 = frag(&X1L[ln][kt * 32 + lq * 8]);
        s8v a1 = frag(&X1L[16 + ln][kt * 32 + lq * 8]);
#pragma unroll
        for (int nt = 0; nt < 4; ++nt) {
            int n = wave * 64 + nt * 16 + ln;
            s8v b = frag(&W1T[n * 320 + kt * 32 + lq * 8]);
            acc1[0][nt] = __builtin_amdgcn_mfma_f32_16x16x32_bf16(a0, b, acc1[0][nt], 0, 0, 0);
            acc1[1][nt] = __builtin_amdgcn_mfma_f32_16x16x32_bf16(a1, b, acc1[1][nt], 0, 0, 0);
        }
    }
#pragma unroll
    for (int nt = 0; nt < 4; ++nt) {
        int col = wave * 64 + nt * 16 + ln;
        float wb = Wb[col];
#pragma unroll
        for (int mt = 0; mt < 2; ++mt)
#pragma unroll
            for (int r = 0; r < 4; ++r)
                hidL[mt * 16 + lq * 4 + r][col] = f2bf(fmaxf(acc1[mt][nt][r] + wb, 0.f));
    }
    __syncthreads();

    int rt[2][4];
#pragma unroll
    for (int mt = 0; mt < 2; ++mt)
#pragma unroll
        for (int r = 0; r < 4; ++r) rt[mt][r] = tgts[mt * 16 + lq * 4 + r];
    float mx[2][4], ls[2][4], tg[2][4]; int am[2][4];
#pragma unroll
    for (int mt = 0; mt < 2; ++mt)
#pragma unroll
        for (int r = 0; r < 4; ++r) { mx[mt][r] = -1e30f; ls[mt][r] = 0.f; tg[mt][r] = 0.f; am[mt][r] = 1 << 30; }

    for (int nt = wave; nt < 50; nt += 4) {
        int n = nt * 16 + ln;
        const unsigned short* wrow = WoT + n * 256;
        f4v a2[2];
        a2[0] = (f4v){0.f, 0.f, 0.f, 0.f}; a2[1] = (f4v){0.f, 0.f, 0.f, 0.f};
#pragma unroll
        for (int kt = 0; kt < 8; ++kt) {
            s8v a0 = frag(&hidL[ln][kt * 32 + lq * 8]);
            s8v a1 = frag(&hidL[16 + ln][kt * 32 + lq * 8]);
            s8v b = frag(&wrow[kt * 32 + lq * 8]);
            a2[0] = __builtin_amdgcn_mfma_f32_16x16x32_bf16(a0, b, a2[0], 0, 0, 0);
            a2[1] = __builtin_amdgcn_mfma_f32_16x16x32_bf16(a1, b, a2[1], 0, 0, 0);
        }
        float bias = Wob[n];
#pragma unroll
        for (int mt = 0; mt < 2; ++mt)
#pragma unroll
            for (int r = 0; r < 4; ++r) {
                float v = a2[mt][r] + bias;
                if (n == rt[mt][r]) tg[mt][r] = v;
                float nm = fmaxf(mx[mt][r], v);
                ls[mt][r] = ls[mt][r] * __expf(mx[mt][r] - nm) + __expf(v - nm);
                if (v > mx[mt][r]) am[mt][r] = n;
                mx[mt][r] = nm;
            }
    }

#pragma unroll
    for (int s = 1; s < 16; s <<= 1) {
#pragma unroll
        for (int mt = 0; mt < 2; ++mt)
#pragma unroll
            for (int r = 0; r < 4; ++r) {
                float mo = __shfl_xor(mx[mt][r], s);
                float lo = __shfl_xor(ls[mt][r], s);
                int   ao = __shfl_xor(am[mt][r], s);
                float to = __shfl_xor(tg[mt][r], s);
                tg[mt][r] += to;
                float nm = fmaxf(mx[mt][r], mo);
                ls[mt][r] = ls[mt][r] * __expf(mx[mt][r] - nm) + lo * __expf(mo - nm);
                if (mo > mx[mt][r] || (mo == mx[mt][r] && ao < am[mt][r])) am[mt][r] = ao;
                mx[mt][r] = nm;
            }
    }
    if (ln == 0) {
#pragma unroll
        for (int mt = 0; mt < 2; ++mt)
#pragma unroll
            for (int r = 0; r < 4; ++r) {
                int row = mt * 16 + lq * 4 + r;
                wred[wave][row][0] = mx[mt][r];
                wred[wave][row][1] = ls[mt][r];
                wred[wave][row][2] = __int_as_float(am[mt][r]);
                wred[wave][row][3] = tg[mt][r];
            }
    }
    __syncthreads();

    float lossv = 0.f, corrv = 0.f;
    if (tid < QG) {
        float m_ = -1e30f, l_ = 0.f, t_ = 0.f; int a_ = 1 << 30;
#pragma unroll
        for (int w = 0; w < 4; ++w) {
            float mo = wred[w][tid][0], lo = wred[w][tid][1], to = wred[w][tid][3];
            int ao = __float_as_int(wred[w][tid][2]);
            t_ += to;
            float nm = fmaxf(m_, mo);
            l_ = l_ * __expf(m_ - nm) + lo * __expf(mo - nm);
            if (mo > m_ || (mo == m_ && ao < a_)) a_ = ao;
            m_ = nm;
        }
        lossv = m_ + logf(l_) - t_;
        corrv = (a_ == tgts[tid]) ? 1.f : 0.f;
    }
    if (wave == 0) {
        for (int s = 32; s; s >>= 1) {
            lossv += __shfl_down(lossv, s);
            corrv += __shfl_down(corrv, s);
        }
        if (tid == 0) {
            int slot = blockIdx.x & 255;
            atomicAdd(&acc[0 * 256 + slot], lossv);
            atomicAdd(&acc[2 * 256 + slot], corrv);
        }
    }
}

// ---------------------------------------------------------------------------
// P head, MFMA. 1520 wgs (95 trow x 16 groups) x 256 thr. 32 rows/wg.
// ---------------------------------------------------------------------------
#define PG 32
__global__ __launch_bounds__(256) void p3(
    const int* __restrict__ wid,
    const unsigned short* __restrict__ tvB,
    const unsigned short* __restrict__ embB,
    const unsigned short* __restrict__ hsb,
    const unsigned short* __restrict__ UwT,
    const float* __restrict__ Ub,
    const float* __restrict__ Usw, const float* __restrict__ Usb,
    float* __restrict__ acc)
{
    __shared__ unsigned short XL[PG][584];
    __shared__ int widL[PG];
    __shared__ float wredp[4][PG];
    const int tid = threadIdx.x;
    const int wave = tid >> 6, lane = tid & 63;
    const int lq = lane >> 4, ln = lane & 15;
    const int trow = blockIdx.x >> 4;
    const int b0 = (blockIdx.x & 15) * PG;
    const int node = (trow == 0) ? 0 : ((trow <= NFWD) ? trow : (TSTEP - trow));

    if (tid < PG) widL[tid] = wid[(b0 + tid) * NNODE + node];
    __syncthreads();

    for (int idx = tid; idx < PG * 32; idx += 256) {
        int m = idx >> 5, c = idx & 31;
        *(int4*)&XL[m][c * 8] = *(const int4*)&embB[widL[m] * HD + c * 8];
    }
    if (trow == 0) {
        int4 z = make_int4(0, 0, 0, 0);
        for (int idx = tid; idx < PG * 32; idx += 256) {
            int m = idx >> 5, c = idx & 31;
            *(int4*)&XL[m][256 + c * 8] = z;
        }
    } else {
        const unsigned short* hrow = hsb + (size_t)(trow - 1) * NTREE * HD;
        for (int idx = tid; idx < PG * 32; idx += 256) {
            int m = idx >> 5, c = idx & 31;
            *(int4*)&XL[m][256 + c * 8] = *(const int4*)&hrow[(b0 + m) * HD + c * 8];
        }
    }
    for (int idx = tid; idx < PG * 8; idx += 256) {
        int m = idx >> 3, c = idx & 7;
        *(int4*)&XL[m][512 + c * 8] = *(const int4*)&tvB[(b0 + m) * LD + c * 8];
    }
    __syncthreads();

    f4v a1[2][4];
#pragma unroll
    for (int mt = 0; mt < 2; ++mt)
#pragma unroll
        for (int nt = 0; nt < 4; ++nt) a1[mt][nt] = (f4v){0.f, 0.f, 0.f, 0.f};
    for (int kt = 0; kt < 18; ++kt) {
        s8v a0 = frag(&XL[ln][kt * 32 + lq * 8]);
        s8v am_ = frag(&XL[16 + ln][kt * 32 + lq * 8]);
#pragma unroll
        for (int nt = 0; nt < 4; ++nt) {
            int n = wave * 64 + nt * 16 + ln;
            s8v b = frag(&UwT[n * 576 + kt * 32 + lq * 8]);
            a1[0][nt] = __builtin_amdgcn_mfma_f32_16x16x32_bf16(a0, b, a1[0][nt], 0, 0, 0);
            a1[1][nt] = __builtin_amdgcn_mfma_f32_16x16x32_bf16(am_, b, a1[1][nt], 0, 0, 0);
        }
    }
    float part[2][4] = {{0, 0, 0, 0}, {0, 0, 0, 0}};
#pragma unroll
    for (int nt = 0; nt < 4; ++nt) {
        int n = wave * 64 + nt * 16 + ln;
        float ub = Ub[n], us = Usw[n];
#pragma unroll
        for (int mt = 0; mt < 2; ++mt)
#pragma unroll
            for (int r = 0; r < 4; ++r)
                part[mt][r] += fmaxf(a1[mt][nt][r] + ub, 0.f) * us;
    }
#pragma unroll
    for (int s = 1; s < 16; s <<= 1) {
#pragma unroll
        for (int mt = 0; mt < 2; ++mt)
#pragma unroll
            for (int r = 0; r < 4; ++r)
                part[mt][r] += __shfl_xor(part[mt][r], s);
    }
    if (ln == 0) {
#pragma unroll
        for (int mt = 0; mt < 2; ++mt)
#pragma unroll
            for (int r = 0; r < 4; ++r)
                wredp[wave][mt * 16 + lq * 4 + r] = part[mt][r];
    }
    __syncthreads();

    float lossv = 0.f, corrv = 0.f;
    if (tid < PG) {
        float p = wredp[0][tid] + wredp[1][tid] + wredp[2][tid] + wredp[3][tid] + Usb[0];
        float tgt = (trow < NFWD) ? 1.f : 0.f;
        lossv = fmaxf(p, 0.f) - p * tgt + log1pf(expf(-fabsf(p)));
        corrv = (((p > 0.f) ? 1 : 0) == ((trow < NFWD) ? 1 : 0)) ? 1.f : 0.f;
    }
    if (wave == 0) {
        for (int s = 32; s; s >>= 1) {
            lossv += __shfl_down(lossv, s);
            corrv += __shfl_down(corrv, s);
        }
        if (tid == 0) {
            int slot = blockIdx.x & 255;
            atomicAdd(&acc[1 * 256 + slot], lossv);
            atomicAdd(&acc[3 * 256 + slot], corrv);
        }
    }
}

__global__ void init_kernel(float* __restrict__ acc) {
    acc[threadIdx.x] = 0.f;   // 1024 slots
}

__global__ void fin_kernel(const float* __restrict__ acc, float* __restrict__ out) {
    const int tid = threadIdx.x;
    const int c = tid >> 6, lane = tid & 63;
    float v = 0.f;
    for (int i = lane; i < 256; i += 64) v += acc[c * 256 + i];
    for (int s = 32; s; s >>= 1) v += __shfl_down(v, s);
    if (lane == 0) {
        const float sc[4] = {1.f / 512.f, 1.f / 512.f, 1.f / 24576.f, 1.f / 48640.f};
        out[c] = v * sc[c];
    }
}

extern "C" void kernel_launch(void* const* d_in, const int* in_sizes, int n_in,
                              void* d_out, int out_size, void* d_ws, size_t ws_size,
                              hipStream_t stream) {
    const int*   wid  = (const int*)  d_in[12];
    const float* tv   = (const float*)d_in[13];
    const float* emb  = (const float*)d_in[14];
    const float* Wz   = (const float*)d_in[15];
    const float* bz   = (const float*)d_in[16];
    const float* Wr   = (const float*)d_in[17];
    const float* Ur   = (const float*)d_in[18];
    const float* br   = (const float*)d_in[19];
    const float* Wh   = (const float*)d_in[20];
    const float* bh   = (const float*)d_in[21];
    const float* Ww   = (const float*)d_in[22];
    const float* Wb   = (const float*)d_in[23];
    const float* Uw   = (const float*)d_in[24];
    const float* Ubias= (const float*)d_in[25];
    const float* Wow  = (const float*)d_in[26];
    const float* Wob  = (const float*)d_in[27];
    const float* Usw  = (const float*)d_in[28];
    const float* Usb  = (const float*)d_in[29];

    char* w = (char*)d_ws;
    float* accb = (float*)w;                                 // 4 KB
    float* xzT  = (float*)(w + 4096);                        // 800*256 f32
    float* xhT  = (float*)(w + 823296);
    float* xrT  = (float*)(w + 1642496);
    unsigned short* WzT2 = (unsigned short*)(w + 2461696);   // [256 n][256 k] bf16
    unsigned short* WhT2 = (unsigned short*)(w + 2592768);
    unsigned short* UrT2 = (unsigned short*)(w + 2723840);
    unsigned short* hsb  = (unsigned short*)(w + 2854912);   // 94*512*256 bf16
    unsigned short* W1T  = (unsigned short*)(w + 27496448);  // [256][320]
    unsigned short* WoT  = (unsigned short*)(w + 27660288);  // [800][256]
    unsigned short* UwT  = (unsigned short*)(w + 28069888);  // [256][576]
    unsigned short* embB = (unsigned short*)(w + 28364800);  // [800][256]
    unsigned short* tvB  = (unsigned short*)(w + 28774400);  // [512][64]

    init_kernel<<<1, 1024, 0, stream>>>(accb);
    prep_xproj<<<VOC / PV, 256, 0, stream>>>(emb, Wz, bz, Wh, bh, Wr, br, xzT, xhT, xrT);
    tcvt<<<256, 256, 0, stream>>>(WzT2, Wz + HD * HD, 256, 256);  // Wz bottom half
    tcvt<<<256, 256, 0, stream>>>(WhT2, Wh + HD * HD, 256, 256);  // Wh bottom half
    tcvt<<<256, 256, 0, stream>>>(UrT2, Ur, 256, 256);
    tcvt<<<256, 256, 0, stream>>>(W1T, Ww, 320, 256);
    tcvt<<<800, 256, 0, stream>>>(WoT, Wow, 256, 800);
    tcvt<<<256, 256, 0, stream>>>(UwT, Uw, 576, 256);
    cvt_bf16<<<800, 256, 0, stream>>>(embB, emb, VOC * HD);
    cvt_bf16<<<128, 256, 0, stream>>>(tvB, tv, NTREE * LD);
    gru3<<<NTREE / 2, 512, 0, stream>>>(wid, xzT, xhT, xrT, WzT2, WhT2, UrT2, hsb);
    q3<<<48 * 16, 256, 0, stream>>>(wid, tvB, hsb, W1T, WoT, Wb, Wob, accb);
    p3<<<95 * 16, 256, 0, stream>>>(wid, tvB, embB, hsb, UwT, Ubias, Usw, Usb, accb);
    fin_kernel<<<1, 256, 0, stream>>>(accb, (float*)d_out);
}

// Round 5
// 525.452 us; speedup vs baseline: 2.0829x; 2.0829x over previous
//
#include <hip/hip_runtime.h>
#include <math.h>

#define NTREE 512
#define NNODE 48
#define HD 256
#define LD 64
#define VOC 800
#define TSTEP 94
#define NFWD 47

typedef __attribute__((ext_vector_type(8))) short s8v;   // 8 bf16 (4 VGPRs)
typedef __attribute__((ext_vector_type(4))) float f4v;   // 4 fp32 acc

__device__ __forceinline__ float sigm(float x) { return 1.f / (1.f + expf(-x)); }

__device__ __forceinline__ float bfu(unsigned short u) {
    union { unsigned int i; float f; } c; c.i = ((unsigned int)u) << 16; return c.f;
}
__device__ __forceinline__ unsigned short f2bf(float f) {
    union { float f; unsigned int u; } c; c.f = f;
    return (unsigned short)((c.u + 0x7fffu + ((c.u >> 16) & 1u)) >> 16);
}
__device__ __forceinline__ s8v frag(const unsigned short* p) {
    union { int4 i; s8v v; } u; u.i = *(const int4*)p; return u.v;
}
__device__ __forceinline__ s8v zfrag() {
    union { int4 i; s8v v; } u; u.i = make_int4(0, 0, 0, 0); return u.v;
}

// ---------------------------------------------------------------------------
// Precompute x-projections for all 800 vocab words (biases folded in).
// ---------------------------------------------------------------------------
#define PV 8
__global__ __launch_bounds__(256) void prep_xproj(
    const float* __restrict__ emb,
    const float* __restrict__ Wz, const float* __restrict__ bz,
    const float* __restrict__ Wh, const float* __restrict__ bh,
    const float* __restrict__ Wr, const float* __restrict__ br,
    float* __restrict__ xzT, float* __restrict__ xhT, float* __restrict__ xrT)
{
    __shared__ float embL[PV][HD];
    const int j = threadIdx.x;
    const int v0 = blockIdx.x * PV;
    for (int r = 0; r < PV; ++r) embL[r][j] = emb[(v0 + r) * HD + j];
    __syncthreads();

    float az[PV], ah[PV], ar[PV];
#pragma unroll
    for (int r = 0; r < PV; ++r) { az[r] = bz[j]; ah[r] = bh[j]; ar[r] = br[j]; }
    for (int i = 0; i < HD; i += 4) {
        float wz0 = Wz[(i + 0) * HD + j], wz1 = Wz[(i + 1) * HD + j];
        float wz2 = Wz[(i + 2) * HD + j], wz3 = Wz[(i + 3) * HD + j];
        float wh0 = Wh[(i + 0) * HD + j], wh1 = Wh[(i + 1) * HD + j];
        float wh2 = Wh[(i + 2) * HD + j], wh3 = Wh[(i + 3) * HD + j];
        float wr0 = Wr[(i + 0) * HD + j], wr1 = Wr[(i + 1) * HD + j];
        float wr2 = Wr[(i + 2) * HD + j], wr3 = Wr[(i + 3) * HD + j];
#pragma unroll
        for (int r = 0; r < PV; ++r) {
            float4 e = *(const float4*)&embL[r][i];
            az[r] += e.x * wz0 + e.y * wz1 + e.z * wz2 + e.w * wz3;
            ah[r] += e.x * wh0 + e.y * wh1 + e.z * wh2 + e.w * wh3;
            ar[r] += e.x * wr0 + e.y * wr1 + e.z * wr2 + e.w * wr3;
        }
    }
#pragma unroll
    for (int r = 0; r < PV; ++r) {
        xzT[(v0 + r) * HD + j] = az[r];
        xhT[(v0 + r) * HD + j] = ah[r];
        xrT[(v0 + r) * HD + j] = ar[r];
    }
}

// Generic transpose-convert: dst[n][k] (bf16) = src[k][n] (f32). grid = N rows.
__global__ void tcvt(unsigned short* __restrict__ dst, const float* __restrict__ src,
                     int K, int N)
{
    int n = blockIdx.x;
    for (int k = threadIdx.x; k < K; k += 256)
        dst[n * K + k] = f2bf(src[k * N + n]);
}

__global__ void cvt_bf16(unsigned short* __restrict__ dst, const float* __restrict__ src, int n)
{
    int idx = blockIdx.x * 256 + threadIdx.x;
    if (idx < n) dst[idx] = f2bf(src[idx]);
}

// ---------------------------------------------------------------------------
// GRU, MFMA, loop-invariant weights hoisted. 256 wgs x 512 threads, 2 trees/wg.
// Phase-A weights (Wz_bot / Wh_bot): 32 s8v frags per wave IN REGISTERS
// (preloaded once; waves 0-3 own Wz tiles, waves 4-7 own Wh tiles).
// Phase-B weights (Ur): 128 KB in LDS, fragment-contiguous [tile][kt][lane]
// so ds_read_b128 is conflict-free. Per step: zero weight traffic.
// ---------------------------------------------------------------------------
__global__ __launch_bounds__(512, 2) void gru4(
    const int* __restrict__ wid,
    const float* __restrict__ xzT, const float* __restrict__ xhT,
    const float* __restrict__ xrT,
    const unsigned short* __restrict__ WzT, const unsigned short* __restrict__ WhT,
    const unsigned short* __restrict__ UrT,
    unsigned short* __restrict__ hsb)
{
    __shared__ float xzL[2][HD], xhL[2][HD], xrL[2][HD];
    __shared__ float azL[2][HD], ahL[2][HD], arL[2][HD];
    __shared__ float mF[2][HD];
    __shared__ unsigned short mB[2][HD], armB[2][HD];
    __shared__ unsigned short urL[16 * 8 * 64 * 8];   // 128 KB: [tile][kt][lane][8]

    const int tid = threadIdx.x;
    const int wave = tid >> 6, lane = tid & 63;
    const int lq = lane >> 4, ln = lane & 15;
    const int trF = tid >> 8, chF = tid & 255;
    const int b0 = blockIdx.x * 2;

    // ---- one-time: Ur -> LDS (fragment-contiguous) ----
#pragma unroll
    for (int s = 0; s < 16; ++s) {
        *(int4*)&urL[((s * 8 + wave) * 64 + lane) * 8] =
            *(const int4*)&UrT[(s * 16 + ln) * HD + wave * 32 + lq * 8];
    }

    // ---- one-time: phase-A weight fragments -> registers (128 VGPRs) ----
    const unsigned short* WT = (wave < 4) ? WzT : WhT;
    const int tb = (wave & 3) * 4;
    s8v wA0[8], wA1[8], wA2[8], wA3[8];
#pragma unroll
    for (int kt = 0; kt < 8; ++kt) {
        const int ko = kt * 32 + lq * 8;
        wA0[kt] = frag(&WT[((tb + 0) * 16 + ln) * HD + ko]);
        wA1[kt] = frag(&WT[((tb + 1) * 16 + ln) * HD + ko]);
        wA2[kt] = frag(&WT[((tb + 2) * 16 + ln) * HD + ko]);
        wA3[kt] = frag(&WT[((tb + 3) * 16 + ln) * HD + ko]);
    }

    for (int t = 0; t < TSTEP; ++t) {
        const bool fwd = t < NFWD;
        const int u = TSTEP - t;
        const int src = fwd ? t : u;
        const int dst = fwd ? (t + 1) : (u - 1);
        const bool hp = (t != 0) && (t != NFWD);

        // ---- stage: gathered x-projections + backtrack h prefetch ----
        {
            const int wsrc = wid[(b0 + trF) * NNODE + src];
            const int wdst = wid[(b0 + trF) * NNODE + dst];
            xzL[trF][chF] = xzT[wsrc * HD + chF];
            xhL[trF][chF] = xhT[wsrc * HD + chF];
            xrL[trF][chF] = xrT[wdst * HD + chF];
        }
        float hsp = 0.f;
        if (!fwd && dst > 0)
            hsp = bfu(hsb[((dst - 1) * NTREE + b0 + trF) * HD + chF]);

        // ---- MFMA phase A: az (waves 0-3, A=mB) / ah (waves 4-7, A=armB) ----
        if (hp) {
            const unsigned short* Ab = (wave < 4) ? &mB[0][0] : &armB[0][0];
            f4v c0 = (f4v){0.f,0.f,0.f,0.f}, c1 = c0, c2 = c0, c3 = c0;
#pragma unroll
            for (int kt = 0; kt < 8; ++kt) {
                s8v a = (ln < 2) ? frag(&Ab[ln * HD + kt * 32 + lq * 8]) : zfrag();
                c0 = __builtin_amdgcn_mfma_f32_16x16x32_bf16(a, wA0[kt], c0, 0, 0, 0);
                c1 = __builtin_amdgcn_mfma_f32_16x16x32_bf16(a, wA1[kt], c1, 0, 0, 0);
                c2 = __builtin_amdgcn_mfma_f32_16x16x32_bf16(a, wA2[kt], c2, 0, 0, 0);
                c3 = __builtin_amdgcn_mfma_f32_16x16x32_bf16(a, wA3[kt], c3, 0, 0, 0);
            }
            if (lq == 0) {
                float* OUT = (wave < 4) ? &azL[0][0] : &ahL[0][0];
                OUT[0 * HD + (tb + 0) * 16 + ln] = c0[0]; OUT[1 * HD + (tb + 0) * 16 + ln] = c0[1];
                OUT[0 * HD + (tb + 1) * 16 + ln] = c1[0]; OUT[1 * HD + (tb + 1) * 16 + ln] = c1[1];
                OUT[0 * HD + (tb + 2) * 16 + ln] = c2[0]; OUT[1 * HD + (tb + 2) * 16 + ln] = c2[1];
                OUT[0 * HD + (tb + 3) * 16 + ln] = c3[0]; OUT[1 * HD + (tb + 3) * 16 + ln] = c3[1];
            }
        }
        __syncthreads();

        // ---- finalize A: z, mt, m_e, h_v store ----
        {
            float az = xzL[trF][chF], ah = xhL[trF][chF], sold = 0.f;
            if (hp) {
                az += azL[trF][chF];
                ah += ahL[trF][chF];
                sold = mF[trF][chF];
            }
            float z = sigm(az), mt = tanhf(ah);
            float me = sold + z * (mt - sold);
            float hv = fwd ? me : (me + hsp);
            hsb[(t * NTREE + b0 + trF) * HD + chF] = f2bf(hv);
            mF[trF][chF] = me;
            mB[trF][chF] = f2bf(me);
        }
        __syncthreads();

        // ---- MFMA phase B: ar = m_e @ Ur (2 tiles/wave, B from LDS) ----
        {
            const int tb2 = wave * 2;
            f4v c0 = (f4v){0.f,0.f,0.f,0.f}, c1 = c0;
#pragma unroll
            for (int kt = 0; kt < 8; ++kt) {
                s8v a = (ln < 2) ? frag(&mB[ln][kt * 32 + lq * 8]) : zfrag();
                s8v b0f = frag(&urL[(((tb2 + 0) * 8 + kt) * 64 + lane) * 8]);
                s8v b1f = frag(&urL[(((tb2 + 1) * 8 + kt) * 64 + lane) * 8]);
                c0 = __builtin_amdgcn_mfma_f32_16x16x32_bf16(a, b0f, c0, 0, 0, 0);
                c1 = __builtin_amdgcn_mfma_f32_16x16x32_bf16(a, b1f, c1, 0, 0, 0);
            }
            if (lq == 0) {
                arL[0][(tb2 + 0) * 16 + ln] = c0[0]; arL[1][(tb2 + 0) * 16 + ln] = c0[1];
                arL[0][(tb2 + 1) * 16 + ln] = c1[0]; arL[1][(tb2 + 1) * 16 + ln] = c1[1];
            }
        }
        __syncthreads();

        // ---- finalize B: r, arm ----
        armB[trF][chF] = f2bf(sigm(arL[trF][chF] + xrL[trF][chF]) * mF[trF][chF]);
        __syncthreads();
    }
}

// ---------------------------------------------------------------------------
// Q head, MFMA. 768 wgs (48 trow x 16 tree-groups) x 256 thr. 32 rows/wg.
// ---------------------------------------------------------------------------
#define QG 32
__global__ __launch_bounds__(256) void q3(
    const int* __restrict__ wid,
    const unsigned short* __restrict__ tvB,
    const unsigned short* __restrict__ hsb,
    const unsigned short* __restrict__ W1T,
    const unsigned short* __restrict__ WoT,
    const float* __restrict__ Wb,
    const float* __restrict__ Wob,
    float* __restrict__ acc)
{
    __shared__ unsigned short X1L[QG][328];
    __shared__ unsigned short hidL[QG][264];
    __shared__ int tgts[QG];
    __shared__ float wred[4][QG][4];
    const int tid = threadIdx.x;
    const int wave = tid >> 6, lane = tid & 63;
    const int lq = lane >> 4, ln = lane & 15;
    const int trow = blockIdx.x >> 4;
    const int b0 = (blockIdx.x & 15) * QG;

    if (tid < QG) tgts[tid] = wid[(b0 + tid) * NNODE + trow];
    if (trow == 0) {
        int4 z = make_int4(0, 0, 0, 0);
        for (int idx = tid; idx < QG * 32; idx += 256) {
            int m = idx >> 5, c = idx & 31;
            *(int4*)&X1L[m][c * 8] = z;
        }
    } else {
        const unsigned short* hrow = hsb + (size_t)(trow - 1) * NTREE * HD;
        for (int idx = tid; idx < QG * 32; idx += 256) {
            int m = idx >> 5, c = idx & 31;
            *(int4*)&X1L[m][c * 8] = *(const int4*)&hrow[(b0 + m) * HD + c * 8];
        }
    }
    for (int idx = tid; idx < QG * 8; idx += 256) {
        int m = idx >> 3, c = idx & 7;
        *(int4*)&X1L[m][256 + c * 8] = *(const int4*)&tvB[(b0 + m) * LD + c * 8];
    }
    __syncthreads();

    f4v acc1[2][4];
#pragma unroll
    for (int mt = 0; mt < 2; ++mt)
#pragma unroll
        for (int nt = 0; nt < 4; ++nt) acc1[mt][nt] = (f4v){0.f, 0.f, 0.f, 0.f};
#pragma unroll
    for (int kt = 0; kt < 10; ++kt) {
        s8v a0 = frag(&X1L[ln][kt * 32 + lq * 8]);
        s8v a1 = frag(&X1L[16 + ln][kt * 32 + lq * 8]);
#pragma unroll
        for (int nt = 0; nt < 4; ++nt) {
            int n = wave * 64 + nt * 16 + ln;
            s8v b = frag(&W1T[n * 320 + kt * 32 + lq * 8]);
            acc1[0][nt] = __builtin_amdgcn_mfma_f32_16x16x32_bf16(a0, b, acc1[0][nt], 0, 0, 0);
            acc1[1][nt] = __builtin_amdgcn_mfma_f32_16x16x32_bf16(a1, b, acc1[1][nt], 0, 0, 0);
        }
    }
#pragma unroll
    for (int nt = 0; nt < 4; ++nt) {
        int col = wave * 64 + nt * 16 + ln;
        float wb = Wb[col];
#pragma unroll
        for (int mt = 0; mt < 2; ++mt)
#pragma unroll
            for (int r = 0; r < 4; ++r)
                hidL[mt * 16 + lq * 4 + r][col] = f2bf(fmaxf(acc1[mt][nt][r] + wb, 0.f));
    }
    __syncthreads();

    int rt[2][4];
#pragma unroll
    for (int mt = 0; mt < 2; ++mt)
#pragma unroll
        for (int r = 0; r < 4; ++r) rt[mt][r] = tgts[mt * 16 + lq * 4 + r];
    float mx[2][4], ls[2][4], tg[2][4]; int am[2][4];
#pragma unroll
    for (int mt = 0; mt < 2; ++mt)
#pragma unroll
        for (int r = 0; r < 4; ++r) { mx[mt][r] = -1e30f; ls[mt][r] = 0.f; tg[mt][r] = 0.f; am[mt][r] = 1 << 30; }

    for (int nt = wave; nt < 50; nt += 4) {
        int n = nt * 16 + ln;
        const unsigned short* wrow = WoT + n * 256;
        f4v a2[2];
        a2[0] = (f4v){0.f, 0.f, 0.f, 0.f}; a2[1] = (f4v){0.f, 0.f, 0.f, 0.f};
#pragma unroll
        for (int kt = 0; kt < 8; ++kt) {
            s8v a0 = frag(&hidL[ln][kt * 32 + lq * 8]);
            s8v a1 = frag(&hidL[16 + ln][kt * 32 + lq * 8]);
            s8v b = frag(&wrow[kt * 32 + lq * 8]);
            a2[0] = __builtin_amdgcn_mfma_f32_16x16x32_bf16(a0, b, a2[0], 0, 0, 0);
            a2[1] = __builtin_amdgcn_mfma_f32_16x16x32_bf16(a1, b, a2[1], 0, 0, 0);
        }
        float bias = Wob[n];
#pragma unroll
        for (int mt = 0; mt < 2; ++mt)
#pragma unroll
            for (int r = 0; r < 4; ++r) {
                float v = a2[mt][r] + bias;
                if (n == rt[mt][r]) tg[mt][r] = v;
                float nm = fmaxf(mx[mt][r], v);
                ls[mt][r] = ls[mt][r] * __expf(mx[mt][r] - nm) + __expf(v - nm);
                if (v > mx[mt][r]) am[mt][r] = n;
                mx[mt][r] = nm;
            }
    }

#pragma unroll
    for (int s = 1; s < 16; s <<= 1) {
#pragma unroll
        for (int mt = 0; mt < 2; ++mt)
#pragma unroll
            for (int r = 0; r < 4; ++r) {
                float mo = __shfl_xor(mx[mt][r], s);
                float lo = __shfl_xor(ls[mt][r], s);
                int   ao = __shfl_xor(am[mt][r], s);
                float to = __shfl_xor(tg[mt][r], s);
                tg[mt][r] += to;
                float nm = fmaxf(mx[mt][r], mo);
                ls[mt][r] = ls[mt][r] * __expf(mx[mt][r] - nm) + lo * __expf(mo - nm);
                if (mo > mx[mt][r] || (mo == mx[mt][r] && ao < am[mt][r])) am[mt][r] = ao;
                mx[mt][r] = nm;
            }
    }
    if (ln == 0) {
#pragma unroll
        for (int mt = 0; mt < 2; ++mt)
#pragma unroll
            for (int r = 0; r < 4; ++r) {
                int row = mt * 16 + lq * 4 + r;
                wred[wave][row][0] = mx[mt][r];
                wred[wave][row][1] = ls[mt][r];
                wred[wave][row][2] = __int_as_float(am[mt][r]);
                wred[wave][row][3] = tg[mt][r];
            }
    }
    __syncthreads();

    float lossv = 0.f, corrv = 0.f;
    if (tid < QG) {
        float m_ = -1e30f, l_ = 0.f, t_ = 0.f; int a_ = 1 << 30;
#pragma unroll
        for (int w = 0; w < 4; ++w) {
            float mo = wred[w][tid][0], lo = wred[w][tid][1], to = wred[w][tid][3];
            int ao = __float_as_int(wred[w][tid][2]);
            t_ += to;
            float nm = fmaxf(m_, mo);
            l_ = l_ * __expf(m_ - nm) + lo * __expf(mo - nm);
            if (mo > m_ || (mo == m_ && ao < a_)) a_ = ao;
            m_ = nm;
        }
        lossv = m_ + logf(l_) - t_;
        corrv = (a_ == tgts[tid]) ? 1.f : 0.f;
    }
    if (wave == 0) {
        for (int s = 32; s; s >>= 1) {
            lossv += __shfl_down(lossv, s);
            corrv += __shfl_down(corrv, s);
        }
        if (tid == 0) {
            int slot = blockIdx.x & 255;
            atomicAdd(&acc[0 * 256 + slot], lossv);
            atomicAdd(&acc[2 * 256 + slot], corrv);
        }
    }
}

// ---------------------------------------------------------------------------
// P head, MFMA. 1520 wgs (95 trow x 16 groups) x 256 thr. 32 rows/wg.
// ---------------------------------------------------------------------------
#define PG 32
__global__ __launch_bounds__(256) void p3(
    const int* __restrict__ wid,
    const unsigned short* __restrict__ tvB,
    const unsigned short* __restrict__ embB,
    const unsigned short* __restrict__ hsb,
    const unsigned short* __restrict__ UwT,
    const float* __restrict__ Ub,
    const float* __restrict__ Usw, const float* __restrict__ Usb,
    float* __restrict__ acc)
{
    __shared__ unsigned short XL[PG][584];
    __shared__ int widL[PG];
    __shared__ float wredp[4][PG];
    const int tid = threadIdx.x;
    const int wave = tid >> 6, lane = tid & 63;
    const int lq = lane >> 4, ln = lane & 15;
    const int trow = blockIdx.x >> 4;
    const int b0 = (blockIdx.x & 15) * PG;
    const int node = (trow == 0) ? 0 : ((trow <= NFWD) ? trow : (TSTEP - trow));

    if (tid < PG) widL[tid] = wid[(b0 + tid) * NNODE + node];
    __syncthreads();

    for (int idx = tid; idx < PG * 32; idx += 256) {
        int m = idx >> 5, c = idx & 31;
        *(int4*)&XL[m][c * 8] = *(const int4*)&embB[widL[m] * HD + c * 8];
    }
    if (trow == 0) {
        int4 z = make_int4(0, 0, 0, 0);
        for (int idx = tid; idx < PG * 32; idx += 256) {
            int m = idx >> 5, c = idx & 31;
            *(int4*)&XL[m][256 + c * 8] = z;
        }
    } else {
        const unsigned short* hrow = hsb + (size_t)(trow - 1) * NTREE * HD;
        for (int idx = tid; idx < PG * 32; idx += 256) {
            int m = idx >> 5, c = idx & 31;
            *(int4*)&XL[m][256 + c * 8] = *(const int4*)&hrow[(b0 + m) * HD + c * 8];
        }
    }
    for (int idx = tid; idx < PG * 8; idx += 256) {
        int m = idx >> 3, c = idx & 7;
        *(int4*)&XL[m][512 + c * 8] = *(const int4*)&tvB[(b0 + m) * LD + c * 8];
    }
    __syncthreads();

    f4v a1[2][4];
#pragma unroll
    for (int mt = 0; mt < 2; ++mt)
#pragma unroll
        for (int nt = 0; nt < 4; ++nt) a1[mt][nt] = (f4v){0.f, 0.f, 0.f, 0.f};
    for (int kt = 0; kt < 18; ++kt) {
        s8v a0 = frag(&XL[ln][kt * 32 + lq * 8]);
        s8v am_ = frag(&XL[16 + ln][kt * 32 + lq * 8]);
#pragma unroll
        for (int nt = 0; nt < 4; ++nt) {
            int n = wave * 64 + nt * 16 + ln;
            s8v b = frag(&UwT[n * 576 + kt * 32 + lq * 8]);
            a1[0][nt] = __builtin_amdgcn_mfma_f32_16x16x32_bf16(a0, b, a1[0][nt], 0, 0, 0);
            a1[1][nt] = __builtin_amdgcn_mfma_f32_16x16x32_bf16(am_, b, a1[1][nt], 0, 0, 0);
        }
    }
    float part[2][4] = {{0, 0, 0, 0}, {0, 0, 0, 0}};
#pragma unroll
    for (int nt = 0; nt < 4; ++nt) {
        int n = wave * 64 + nt * 16 + ln;
        float ub = Ub[n], us = Usw[n];
#pragma unroll
        for (int mt = 0; mt < 2; ++mt)
#pragma unroll
            for (int r = 0; r < 4; ++r)
                part[mt][r] += fmaxf(a1[mt][nt][r] + ub, 0.f) * us;
    }
#pragma unroll
    for (int s = 1; s < 16; s <<= 1) {
#pragma unroll
        for (int mt = 0; mt < 2; ++mt)
#pragma unroll
            for (int r = 0; r < 4; ++r)
                part[mt][r] += __shfl_xor(part[mt][r], s);
    }
    if (ln == 0) {
#pragma unroll
        for (int mt = 0; mt < 2; ++mt)
#pragma unroll
            for (int r = 0; r < 4; ++r)
                wredp[wave][mt * 16 + lq * 4 + r] = part[mt][r];
    }
    __syncthreads();

    float lossv = 0.f, corrv = 0.f;
    if (tid < PG) {
        float p = wredp[0][tid] + wredp[1][tid] + wredp[2][tid] + wredp[3][tid] + Usb[0];
        float tgt = (trow < NFWD) ? 1.f : 0.f;
        lossv = fmaxf(p, 0.f) - p * tgt + log1pf(expf(-fabsf(p)));
        corrv = (((p > 0.f) ? 1 : 0) == ((trow < NFWD) ? 1 : 0)) ? 1.f : 0.f;
    }
    if (wave == 0) {
        for (int s = 32; s; s >>= 1) {
            lossv += __shfl_down(lossv, s);
            corrv += __shfl_down(corrv, s);
        }
        if (tid == 0) {
            int slot = blockIdx.x & 255;
            atomicAdd(&acc[1 * 256 + slot], lossv);
            atomicAdd(&acc[3 * 256 + slot], corrv);
        }
    }
}

__global__ void init_kernel(float* __restrict__ acc) {
    acc[threadIdx.x] = 0.f;   // 1024 slots
}

__global__ void fin_kernel(const float* __restrict__ acc, float* __restrict__ out) {
    const int tid = threadIdx.x;
    const int c = tid >> 6, lane = tid & 63;
    float v = 0.f;
    for (int i = lane; i < 256; i += 64) v += acc[c * 256 + i];
    for (int s = 32; s; s >>= 1) v += __shfl_down(v, s);
    if (lane == 0) {
        const float sc[4] = {1.f / 512.f, 1.f / 512.f, 1.f / 24576.f, 1.f / 48640.f};
        out[c] = v * sc[c];
    }
}

extern "C" void kernel_launch(void* const* d_in, const int* in_sizes, int n_in,
                              void* d_out, int out_size, void* d_ws, size_t ws_size,
                              hipStream_t stream) {
    const int*   wid  = (const int*)  d_in[12];
    const float* tv   = (const float*)d_in[13];
    const float* emb  = (const float*)d_in[14];
    const float* Wz   = (const float*)d_in[15];
    const float* bz   = (const float*)d_in[16];
    const float* Wr   = (const float*)d_in[17];
    const float* Ur   = (const float*)d_in[18];
    const float* br   = (const float*)d_in[19];
    const float* Wh   = (const float*)d_in[20];
    const float* bh   = (const float*)d_in[21];
    const float* Ww   = (const float*)d_in[22];
    const float* Wb   = (const float*)d_in[23];
    const float* Uw   = (const float*)d_in[24];
    const float* Ubias= (const float*)d_in[25];
    const float* Wow  = (const float*)d_in[26];
    const float* Wob  = (const float*)d_in[27];
    const float* Usw  = (const float*)d_in[28];
    const float* Usb  = (const float*)d_in[29];

    char* w = (char*)d_ws;
    float* accb = (float*)w;                                 // 4 KB
    float* xzT  = (float*)(w + 4096);                        // 800*256 f32
    float* xhT  = (float*)(w + 823296);
    float* xrT  = (float*)(w + 1642496);
    unsigned short* WzT2 = (unsigned short*)(w + 2461696);   // [256 n][256 k] bf16
    unsigned short* WhT2 = (unsigned short*)(w + 2592768);
    unsigned short* UrT2 = (unsigned short*)(w + 2723840);
    unsigned short* hsb  = (unsigned short*)(w + 2854912);   // 94*512*256 bf16
    unsigned short* W1T  = (unsigned short*)(w + 27496448);  // [256][320]
    unsigned short* WoT  = (unsigned short*)(w + 27660288);  // [800][256]
    unsigned short* UwT  = (unsigned short*)(w + 28069888);  // [256][576]
    unsigned short* embB = (unsigned short*)(w + 28364800);  // [800][256]
    unsigned short* tvB  = (unsigned short*)(w + 28774400);  // [512][64]

    init_kernel<<<1, 1024, 0, stream>>>(accb);
    prep_xproj<<<VOC / PV, 256, 0, stream>>>(emb, Wz, bz, Wh, bh, Wr, br, xzT, xhT, xrT);
    tcvt<<<256, 256, 0, stream>>>(WzT2, Wz + HD * HD, 256, 256);  // Wz bottom half
    tcvt<<<256, 256, 0, stream>>>(WhT2, Wh + HD * HD, 256, 256);  // Wh bottom half
    tcvt<<<256, 256, 0, stream>>>(UrT2, Ur, 256, 256);
    tcvt<<<256, 256, 0, stream>>>(W1T, Ww, 320, 256);
    tcvt<<<800, 256, 0, stream>>>(WoT, Wow, 256, 800);
    tcvt<<<256, 256, 0, stream>>>(UwT, Uw, 576, 256);
    cvt_bf16<<<800, 256, 0, stream>>>(embB, emb, VOC * HD);
    cvt_bf16<<<128, 256, 0, stream>>>(tvB, tv, NTREE * LD);
    gru4<<<NTREE / 2, 512, 0, stream>>>(wid, xzT, xhT, xrT, WzT2, WhT2, UrT2, hsb);
    q3<<<48 * 16, 256, 0, stream>>>(wid, tvB, hsb, W1T, WoT, Wb, Wob, accb);
    p3<<<95 * 16, 256, 0, stream>>>(wid, tvB, embB, hsb, UwT, Ubias, Usw, Usb, accb);
    fin_kernel<<<1, 256, 0, stream>>>(accb, (float*)d_out);
}